// Round 16
// baseline (116.025 us; speedup 1.0000x reference)
//
#include <hip/hip_runtime.h>
#include <hip/hip_bf16.h>

// MultiLinear: y[b,g,o] = sum_i x[b,g,i] * W[g,o,i] + bias[g,o]
// B=4096, G=16, DIN=512, DOUT=512, fp32 in/out.
// R16 = R15 schedule (verified: X-read-once BN=512, B bf16-DMA, chunk-XOR
// conflict-free LDS, counted vmcnt, 1 raw barrier/K-tile) at 2-blocks/CU
// geometry: BM=64, BK=32 -> LDS 72 KB (<=80), acc 64 AGPR, regs ~115 <= 128
// (launch_bounds(512,4)). Two INDEPENDENT blocks per CU fill each other's
// barrier/drain bubbles; X traffic stays minimal (BN=512 unchanged).

#define BATCH 4096
#define NGRP  16
#define DIN   512
#define DOUT  512

#define BM 64
#define BN 512
#define BK 32
#define NT (DIN / BK)   // 16 K-tiles

typedef __bf16 bf16x8 __attribute__((ext_vector_type(8)));
typedef __bf16 bf16x4 __attribute__((ext_vector_type(4)));
typedef float  f32x4  __attribute__((ext_vector_type(4)));
typedef const __attribute__((address_space(1))) void gas_void;
typedef __attribute__((address_space(3))) void las_void;

// ---------- prepass: W fp32 -> bf16 into d_ws ----------
__global__ __launch_bounds__(256)
void wcvt_kernel(const float* __restrict__ W, __bf16* __restrict__ Wb) {
    const int i = (blockIdx.x * 256 + threadIdx.x) * 8;
    f32x4 a = *(const f32x4*)(W + i);
    f32x4 b = *(const f32x4*)(W + i + 4);
    bf16x8 v;
#pragma unroll
    for (int j = 0; j < 4; ++j) { v[j] = (__bf16)a[j]; v[j + 4] = (__bf16)b[j]; }
    *(bf16x8*)(Wb + i) = v;
}

// ---------- main GEMM ----------
__global__ __launch_bounds__(512, 4)
void MultiLinear_48498770706571_kernel(const float* __restrict__ X,
                                       const __bf16* __restrict__ Wb,
                                       const float* __restrict__ Bias,
                                       float* __restrict__ Y) {
    // 1024 blocks / 8 XCDs = 128 consecutive tiles (2 full groups) per XCD.
    const int bid = (blockIdx.x & 7) * 128 + (blockIdx.x >> 3);
    const int g   = bid >> 6;          // 64 m-tiles per group, 1 n-tile
    const int mt  = bid & 63;
    const int bm0 = mt * BM;

    __shared__ __bf16 As[2][BM * BK];    // 8 KB: 64B rows, chunk-XOR swizzled
    __shared__ __bf16 BsF[2][BN * BK];   // 64 KB: linear, DMA, chunk-swz

    const int tid  = threadIdx.x;
    const int lane = tid & 63;
    const int w    = tid >> 6;        // 0..7
    const int wn   = w * 64;          // wave n-offset (wm = 0 for all)
    const int l15  = lane & 15;
    const int q    = lane >> 4;       // 0..3 = 16B k-chunk of the MFMA frag

    // A staging: 8 thr/row, 4 floats (16 B) each; 64 rows by 512 threads.
    const int srow = tid >> 3;        // 0..63
    const int sc   = (tid & 7) >> 1;  // logical 16B-chunk 0..3 within row
    const int sh   = tid & 1;         // 8B half within chunk
    const float* pA = X + (size_t)(bm0 + srow) * (NGRP * DIN) + g * DIN + (tid & 7) * 4;

    // B DMA geometry: per instr 16 rows x 64 B (1 KB); 4 instrs per wave.
    const int drow_l = lane >> 2;     // 0..15 row within instr
    const int dch    = lane & 3;      // 16B chunk within row
    const __bf16* wbase = Wb + (size_t)g * (DOUT * DIN);

    f32x4 ra;   // 4 VGPRs in flight (A only; B is DMA)

#define ISSUE_A(k0) do { ra = *(const f32x4*)(pA + (k0)); } while (0)

    // A write: row srow, logical chunk sc (half sh) -> phys chunk sc^(srow&3)
#define CVT_WRITE_A(buf)                                                   \
    do {                                                                   \
        bf16x4 v;                                                          \
        _Pragma("unroll")                                                  \
        for (int j = 0; j < 4; ++j) v[j] = (__bf16)ra[j];                  \
        *(bf16x4*)&As[buf][srow * BK + ((sc ^ (srow & 3)) << 3) + sh * 4] = v; \
    } while (0)

    // B: LDS linear dest; global source pre-swizzled; reads swizzle back.
#define DMA_B(kt, buf)                                                     \
    do {                                                                   \
        const size_t k0 = (size_t)(kt) * BK;                               \
        _Pragma("unroll")                                                  \
        for (int qq = 0; qq < 4; ++qq) {                                   \
            const int row = (w << 6) + (qq << 4) + drow_l;                 \
            const __bf16* gp = wbase + (size_t)row * DIN + k0              \
                               + ((dch ^ (row & 3)) << 3);                 \
            __builtin_amdgcn_global_load_lds(                              \
                (gas_void*)gp,                                             \
                (las_void*)&BsF[buf][((w << 6) + (qq << 4)) * BK],         \
                16, 0, 0);                                                 \
        }                                                                  \
    } while (0)

#define COMPUTE(buf)                                                       \
    do {                                                                   \
        bf16x8 af[4], bfr[4];                                              \
        _Pragma("unroll")                                                  \
        for (int mi = 0; mi < 4; ++mi) {                                   \
            const int row = mi * 16 + l15;                                 \
            const int ch  = q ^ (row & 3);                                 \
            af[mi] = *(const bf16x8*)&As[buf][row * BK + (ch << 3)];       \
        }                                                                  \
        _Pragma("unroll")                                                  \
        for (int ni = 0; ni < 4; ++ni) {                                   \
            const int brow = wn + ni * 16 + l15;                           \
            const int ch   = q ^ (brow & 3);                               \
            bfr[ni] = *(const bf16x8*)&BsF[buf][brow * BK + (ch << 3)];    \
        }                                                                  \
        _Pragma("unroll")                                                  \
        for (int mi = 0; mi < 4; ++mi)                                     \
            _Pragma("unroll")                                              \
            for (int ni = 0; ni < 4; ++ni)                                 \
                acc[mi][ni] = __builtin_amdgcn_mfma_f32_16x16x32_bf16(     \
                    af[mi], bfr[ni], acc[mi][ni], 0, 0, 0);                \
    } while (0)

    f32x4 acc[4][4];
#pragma unroll
    for (int mi = 0; mi < 4; ++mi)
#pragma unroll
        for (int ni = 0; ni < 4; ++ni) acc[mi][ni] = f32x4{0.f, 0.f, 0.f, 0.f};

    // prologue: A(0) + DMA B(0) into buf0; write A(0); prefetch A(1).
    ISSUE_A(0);
    DMA_B(0, 0);
    CVT_WRITE_A(0);      // compiler waits ra(0) (vmcnt(4): DMA(0) in flight)
    ISSUE_A(BK);         // outstanding: DMA(0)[4] + ra(1)[1]

    for (int kt = 0; kt < NT; ++kt) {
        const int cur = kt & 1;
        // Drain DMA(kt): outstanding = DMA(kt)[4 oldest] + ra(kt+1)[1 newer].
        if (kt + 1 < NT)
            asm volatile("s_waitcnt vmcnt(1)" ::: "memory");
        else
            asm volatile("s_waitcnt vmcnt(0)" ::: "memory");  // tail: DMA only
        asm volatile("s_waitcnt lgkmcnt(0)" ::: "memory");
        __builtin_amdgcn_s_barrier();

        // after barrier: all waves done reading buf cur^1 -> WAR-safe refill.
        if (kt + 1 < NT) DMA_B(kt + 1, cur ^ 1);

        COMPUTE(cur);

        if (kt + 1 < NT) {
            CVT_WRITE_A(cur ^ 1);   // drains ra(kt+1) (vmcnt(4)), DMA in flight
            if (kt + 2 < NT) ISSUE_A((kt + 2) * BK);
        }
    }

    // epilogue: C/D layout col = lane&15, row = (lane>>4)*4 + j (verified R1)
    const int r0 = (lane >> 4) * 4;
    const int c  = lane & 15;
    float bias_n[4];
#pragma unroll
    for (int ni = 0; ni < 4; ++ni)
        bias_n[ni] = Bias[g * DOUT + wn + ni * 16 + c];
#pragma unroll
    for (int mi = 0; mi < 4; ++mi) {
#pragma unroll
        for (int j = 0; j < 4; ++j) {
            const int row = bm0 + mi * 16 + r0 + j;
            float* yrow = Y + (size_t)row * (NGRP * DOUT) + g * DOUT + wn;
#pragma unroll
            for (int ni = 0; ni < 4; ++ni)
                yrow[ni * 16 + c] = acc[mi][ni][j] + bias_n[ni];
        }
    }
#undef ISSUE_A
#undef CVT_WRITE_A
#undef DMA_B
#undef COMPUTE
}

extern "C" void kernel_launch(void* const* d_in, const int* in_sizes, int n_in,
                              void* d_out, int out_size, void* d_ws, size_t ws_size,
                              hipStream_t stream) {
    const float* X    = (const float*)d_in[0];
    const float* W    = (const float*)d_in[1];
    const float* Bias = (const float*)d_in[2];
    float* Y          = (float*)d_out;
    __bf16* Wb        = (__bf16*)d_ws;   // 8 MB scratch

    // prepass: 16*512*512 = 4M elems / (256 thr * 8 elems) = 2048 blocks
    wcvt_kernel<<<2048, 256, 0, stream>>>(W, Wb);

    const int grid = NGRP * (BATCH / BM);  // 16*64 = 1024
    MultiLinear_48498770706571_kernel<<<grid, 512, 0, stream>>>(X, Wb, Bias, Y);
}